// Round 6
// baseline (150.981 us; speedup 1.0000x reference)
//
#include <hip/hip_runtime.h>

typedef unsigned short u16;
typedef unsigned int u32;
typedef __bf16 bf16x8 __attribute__((ext_vector_type(8)));
typedef float f32x4 __attribute__((ext_vector_type(4)));

#define MFMA16(a, b, c) __builtin_amdgcn_mfma_f32_16x16x32_bf16(a, b, c, 0, 0, 0)
#define EXP2(x) __builtin_amdgcn_exp2f(x)

typedef const void __attribute__((address_space(1)))* gas1_t;
typedef void __attribute__((address_space(3)))* las3_t;

__device__ __forceinline__ void gload16(const void* g, void* l) {
  __builtin_amdgcn_global_load_lds((gas1_t)g, (las3_t)l, 16, 0, 0);
}

__device__ __forceinline__ u16 f2bf(float f) {
  union { float f; u32 u; } v; v.f = f;
  u32 r = v.u + 0x7FFFu + ((v.u >> 16) & 1u);
  return (u16)(r >> 16);
}

// fast tanh via native exp2: tanh(x) = (e^2x - 1)/(e^2x + 1); bf16-accurate
__device__ __forceinline__ float fast_tanh(float x) {
  float xc = fminf(fmaxf(x, -20.f), 20.f);
  float t = EXP2(xc * 2.885390081777927f);  // 2*log2(e)
  return (t - 1.0f) * __builtin_amdgcn_rcpf(t + 1.0f);
}

// ---------------- elementwise f32 -> bf16 convert (8 elems/thread) ----------
__global__ __launch_bounds__(256) void cvt_kernel(const float* __restrict__ in,
                                                  u16* __restrict__ out, int n8) {
  int i = blockIdx.x * blockDim.x + threadIdx.x;
  int stride = gridDim.x * blockDim.x;
  for (; i < n8; i += stride) {
    const float4* p = (const float4*)(in + (size_t)i * 8);
    float4 a = p[0], b = p[1];
    u16 t[8];
    t[0] = f2bf(a.x); t[1] = f2bf(a.y); t[2] = f2bf(a.z); t[3] = f2bf(a.w);
    t[4] = f2bf(b.x); t[5] = f2bf(b.y); t[6] = f2bf(b.z); t[7] = f2bf(b.w);
    *(uint4*)(out + (size_t)i * 8) = *(uint4*)t;
  }
}

// ------------- w [H][E=1024][D=128] f32 -> wT [H][D][E] bf16 ----------------
__global__ __launch_bounds__(256) void wtrans_kernel(const float* __restrict__ w,
                                                     u16* __restrict__ wT) {
  __shared__ float t[64][65];
  int h = blockIdx.z;
  int e0 = blockIdx.x * 64, d0 = blockIdx.y * 64;
  const float* src = w + (size_t)h * 1024 * 128;
  u16* dst = wT + (size_t)h * 128 * 1024;
  int tid = threadIdx.x;
  {
    int row = tid >> 2, c0 = (tid & 3) * 16;
#pragma unroll
    for (int i = 0; i < 4; ++i) {
      float4 v = *(const float4*)(src + (size_t)(e0 + row) * 128 + d0 + c0 + i * 4);
      t[row][c0 + i * 4 + 0] = v.x;
      t[row][c0 + i * 4 + 1] = v.y;
      t[row][c0 + i * 4 + 2] = v.z;
      t[row][c0 + i * 4 + 3] = v.w;
    }
  }
  __syncthreads();
  {
    int dl = tid >> 2, c0 = (tid & 3) * 16;
    u16 tmp[16];
#pragma unroll
    for (int i = 0; i < 16; ++i) tmp[i] = f2bf(t[c0 + i][dl]);
    u16* o = dst + (size_t)(d0 + dl) * 1024 + e0 + c0;
    *(uint4*)o = *(uint4*)tmp;
    *(uint4*)(o + 8) = *(uint4*)(tmp + 8);
  }
}

// ---- shared BM=128 x BN=(32*NF) tile GEMM core, BK=32, double-buffered -----
// A: [M][K] row-major bf16, B: [N][K] row-major bf16 (B^T layout).
// LDS tile for X rows x 32 K packed as [X/2][8 slots of 16B]: two row-halves
// side by side, 128B LDS rows, slot = ((half<<2)|kchunk) ^ (r&7). Bank-even.
// 32 KB (NF=4) / 24 KB (NF=2) total -> 4 blocks/CU.
template <int NF>
__device__ __forceinline__ void vwait_next() {
  if constexpr (NF == 4) asm volatile("s_waitcnt vmcnt(4)" ::: "memory");
  else                   asm volatile("s_waitcnt vmcnt(3)" ::: "memory");
}

template <int NF>
__device__ __forceinline__ void gemm_core_bk32(const u16* Abase, const u16* Bbase,
                                               int K,
                                               u16* A0, u16* B0, u16* A1, u16* B1,
                                               f32x4 (&acc)[4][NF]) {
  const int tid = threadIdx.x, lane = tid & 63, wid = tid >> 6;
  const int wr = wid >> 1, wc = wid & 1;
  const int l15 = lane & 15, g = lane >> 4;
  const int nkt = K >> 5;  // assumed even, >= 2

  // stage one X-row tile (X=128 -> NI=2 instrs/wave; X=64 -> NI=1)
#define STG(dst, srcb, X, NI, kt_)                                              \
  _Pragma("unroll") for (int i_ = 0; i_ < (NI); ++i_) {                         \
    int c = (wid * (NI) + i_) * 64 + lane;                                      \
    int rp = c >> 3, ps = c & 7, ls = ps ^ (rp & 7);                            \
    int row = rp + ((X) / 2) * (ls >> 2);                                       \
    gload16((const char*)(srcb) + (size_t)row * (size_t)(K * 2) +               \
                (kt_) * 64 + (ls & 3) * 16,                                     \
            (char*)(dst) + (wid * (NI) + i_) * 1024);                           \
  }

#define CMP(Al, Bl)                                                             \
  do {                                                                          \
    bf16x8 af[4], bb[NF];                                                       \
    __builtin_amdgcn_s_setprio(1);                                              \
    _Pragma("unroll") for (int f = 0; f < 4; ++f) {                             \
      int rp = f * 16 + l15;                                                    \
      af[f] = *(const bf16x8*)((char*)(Al) + rp * 128 +                         \
                               ((((wr << 2) | g) ^ (rp & 7)) << 4));            \
    }                                                                           \
    _Pragma("unroll") for (int f = 0; f < NF; ++f) {                            \
      int rp = f * 16 + l15;                                                    \
      bb[f] = *(const bf16x8*)((char*)(Bl) + rp * 128 +                         \
                               ((((wc << 2) | g) ^ (rp & 7)) << 4));            \
    }                                                                           \
    _Pragma("unroll") for (int mf = 0; mf < 4; ++mf)                            \
      _Pragma("unroll") for (int nf = 0; nf < NF; ++nf)                         \
        acc[mf][nf] = MFMA16(af[mf], bb[nf], acc[mf][nf]);                      \
    __builtin_amdgcn_s_setprio(0);                                              \
  } while (0)

  STG(A0, Abase, 128, 2, 0);
  STG(B0, Bbase, NF * 32, NF / 2, 0);
  for (int it = 0; it < nkt / 2 - 1; ++it) {
    STG(A1, Abase, 128, 2, 2 * it + 1);
    STG(B1, Bbase, NF * 32, NF / 2, 2 * it + 1);
    vwait_next<NF>();                       // tile 2it drained; 2it+1 in flight
    __builtin_amdgcn_s_barrier();
    CMP(A0, B0);
    __builtin_amdgcn_s_barrier();           // all waves done reading buf0
    STG(A0, Abase, 128, 2, 2 * it + 2);
    STG(B0, Bbase, NF * 32, NF / 2, 2 * it + 2);
    vwait_next<NF>();
    __builtin_amdgcn_s_barrier();
    CMP(A1, B1);
    __builtin_amdgcn_s_barrier();
  }
  STG(A1, Abase, 128, 2, nkt - 1);
  STG(B1, Bbase, NF * 32, NF / 2, nkt - 1);
  vwait_next<NF>();
  __builtin_amdgcn_s_barrier();
  CMP(A0, B0);
  asm volatile("s_waitcnt vmcnt(0)" ::: "memory");
  __builtin_amdgcn_s_barrier();
  CMP(A1, B1);
#undef STG
#undef CMP
}

// ------------- stage 1: per-head projection + tanh -> bf16 ------------------
// grid (64 m-tiles, 8 heads, 2 tensors); BN=128 (NF=4); LDS 32 KB -> 4 blk/CU
__global__ __launch_bounds__(256, 4) void gemm_tanh_kernel(
    const u16* __restrict__ Ak, const u16* __restrict__ Aq,
    const u16* __restrict__ wTk, const u16* __restrict__ wTq,
    u16* __restrict__ kxo, u16* __restrict__ qxo) {
  __shared__ alignas(16) u16 A0[64 * 64], B0[64 * 64];
  __shared__ alignas(16) u16 A1[64 * 64], B1[64 * 64];
  const u16* A; const u16* W; u16* C;
  if (blockIdx.z == 0) { A = Ak; W = wTk; C = kxo; }
  else { A = Aq; W = wTq; C = qxo; }
  int h = blockIdx.y;
  int mBase = blockIdx.x * 128;
  f32x4 acc[4][4];
#pragma unroll
  for (int i = 0; i < 4; ++i)
#pragma unroll
    for (int j = 0; j < 4; ++j) acc[i][j] = (f32x4){0.f, 0.f, 0.f, 0.f};
  gemm_core_bk32<4>(A + (size_t)mBase * 1024, W + (size_t)h * 128 * 1024, 1024,
                    A0, B0, A1, B1, acc);
  const int lane = threadIdx.x & 63, wid = threadIdx.x >> 6;
  const int wr = wid >> 1, wc = wid & 1;
  u16* Ch = C + (size_t)h * 8192 * 128;
#pragma unroll
  for (int mf = 0; mf < 4; ++mf)
#pragma unroll
    for (int nf = 0; nf < 4; ++nf)
#pragma unroll
      for (int j = 0; j < 4; ++j) {
        int m = mBase + wr * 64 + mf * 16 + ((lane >> 4) << 2) + j;
        int d = wc * 64 + nf * 16 + (lane & 15);
        Ch[(size_t)m * 128 + d] = f2bf(fast_tanh(acc[mf][nf][j]));
      }
}

// ------------- kx [h][b*1024+s][128] -> kxT [h][b][128][1024] ---------------
// grid (16 s-tiles, 2 d-tiles, 64 hb)
__global__ __launch_bounds__(256) void transpose_kernel(const u16* __restrict__ kx,
                                                        u16* __restrict__ kxT) {
  __shared__ u16 t[64][72];
  int hb = blockIdx.z;
  const u16* src = kx + (size_t)hb * 1024 * 128;
  u16* dst = kxT + (size_t)hb * 128 * 1024;
  int s0 = blockIdx.x * 64, d0 = blockIdx.y * 64;
  int tid = threadIdx.x;
#pragma unroll
  for (int r = 0; r < 2; ++r) {
    int row = r * 32 + (tid >> 3), c8 = (tid & 7) * 8;
    uint4 v = *(const uint4*)(src + (size_t)(s0 + row) * 128 + d0 + c8);
    *(uint4*)&t[row][c8] = v;
  }
  __syncthreads();
#pragma unroll
  for (int r = 0; r < 2; ++r) {
    int dl = r * 32 + (tid >> 3), s8 = (tid & 7) * 8;
    u16 tmp[8];
#pragma unroll
    for (int i = 0; i < 8; ++i) tmp[i] = t[s8 + i][dl];
    *(uint4*)(dst + (size_t)(d0 + dl) * 1024 + s0 + s8) = *(uint4*)tmp;
  }
}

// ---------------------------- flash attention -------------------------------
// grid (64 hb, 8 q-tiles); 4 waves x 32 q-rows; KV tiles of 64
// Swapped QK^T (S^T = mfma(K, Q)) -> P packs in-register, 8 x ds_write_b64.
// No-max softmax (tanh-bounded scores). Dbuf K/V staging with counted vmcnt.
__global__ __launch_bounds__(256, 2) void attn_kernel(const u16* __restrict__ qx,
                                                      const u16* __restrict__ kx,
                                                      const u16* __restrict__ kxT,
                                                      u16* __restrict__ X) {
  __shared__ alignas(16) u16 Klds[2][64 * 128];   // [s][d], 16 chunks/row, swizzled
  __shared__ alignas(16) u16 Vlds[2][128 * 64];   // [d][s], 8 chunks/row, swizzled
  __shared__ alignas(16) u16 Plds[4][32 * 64];    // per-wave [q][s], slot16-swizzled
  const int tid = threadIdx.x, lane = tid & 63, wid = tid >> 6;
  const int g = lane >> 4;                        // 16-lane group 0..3
  const int hb = blockIdx.x, qt = blockIdx.y, h = hb >> 3, b = hb & 7;
  const u16* qxh = qx + ((size_t)h * 8192 + (size_t)b * 1024) * 128;
  const u16* kxh = kx + ((size_t)h * 8192 + (size_t)b * 1024) * 128;
  const u16* kxTh = kxT + (size_t)hb * 128 * 1024;
  const int q0 = qt * 128 + wid * 32;
  const float SC = 0.08838834764831845f * 1.44269504088896340f; // 1/sqrt(128)*log2e

#define STAGE(buf, kt_)                                                        \
  do {                                                                         \
    _Pragma("unroll") for (int i_ = 0; i_ < 4; ++i_) {                         \
      int cIdx = (wid * 4 + i_) * 64 + lane;                                   \
      {                                                                        \
        int row = cIdx >> 4, slot = cIdx & 15;                                 \
        int src = slot ^ (row & 7);                                            \
        gload16((const char*)kxh + (size_t)((kt_) * 64 + row) * 256 + src * 16,\
                (char*)&Klds[buf][0] + (wid * 4 + i_) * 1024);                 \
      }                                                                        \
      {                                                                        \
        int row = cIdx >> 3, slot = cIdx & 7;                                  \
        int src = slot ^ (row & 7);                                            \
        gload16((const char*)kxTh + (size_t)row * 2048 + (kt_) * 128 + src * 16,\
                (char*)&Vlds[buf][0] + (wid * 4 + i_) * 1024);                 \
      }                                                                        \
    }                                                                          \
  } while (0)

  bf16x8 qa[2][4];
#pragma unroll
  for (int m = 0; m < 2; ++m)
#pragma unroll
    for (int kc = 0; kc < 4; ++kc)
      qa[m][kc] = *(const bf16x8*)(qxh + (size_t)(q0 + m * 16 + (lane & 15)) * 128
                                   + kc * 32 + g * 8);

  f32x4 os[2][8];
#pragma unroll
  for (int i = 0; i < 2; ++i)
#pragma unroll
    for (int j = 0; j < 8; ++j) os[i][j] = (f32x4){0.f, 0.f, 0.f, 0.f};
  float lsum[2] = {0.f, 0.f};   // partial row-sums for q = 16m + (lane&15)

  u16* Pw = &Plds[wid][0];

  STAGE(0, 0);  // prologue: tile 0 in flight

  for (int kt = 0; kt < 16; ++kt) {
    const int cur = kt & 1;
    if (kt < 15) {
      STAGE(cur ^ 1, kt + 1);                       // issue next tile (8 loads)
      asm volatile("s_waitcnt vmcnt(8)" ::: "memory");  // tile kt drained
    } else {
      asm volatile("s_waitcnt vmcnt(0)" ::: "memory");
    }
    __builtin_amdgcn_s_barrier();                   // tile kt visible to all

    const u16* Kc = &Klds[cur][0];
    const u16* Vc = &Vlds[cur][0];

    // S^T = K Q^T: sa[t][m][j] = S[q = 16m+(lane&15)][s = 16t + 4g + j]
    f32x4 sa[4][2];
#pragma unroll
    for (int i = 0; i < 4; ++i)
#pragma unroll
      for (int j = 0; j < 2; ++j) sa[i][j] = (f32x4){0.f, 0.f, 0.f, 0.f};
    __builtin_amdgcn_s_setprio(1);
#pragma unroll
    for (int kc = 0; kc < 4; ++kc) {
      bf16x8 kb[4];
#pragma unroll
      for (int t = 0; t < 4; ++t) {
        int row = t * 16 + (lane & 15);
        int ch = kc * 4 + g;
        kb[t] = *(const bf16x8*)(Kc + row * 128 + ((ch ^ (row & 7)) << 3));
      }
#pragma unroll
      for (int t = 0; t < 4; ++t)
#pragma unroll
        for (int m = 0; m < 2; ++m)
          sa[t][m] = MFMA16(kb[t], qa[m][kc], sa[t][m]);
    }
    __builtin_amdgcn_s_setprio(0);

    // no-max softmax: p = exp2(s*SC); pack 4 bf16 -> one ds_write_b64.
#pragma unroll
    for (int m = 0; m < 2; ++m) {
      int q = m * 16 + (lane & 15);
      int rowb = q * 128, q7 = q & 7;
#pragma unroll
      for (int t = 0; t < 4; ++t) {
        float p0 = EXP2(sa[t][m][0] * SC);
        float p1 = EXP2(sa[t][m][1] * SC);
        float p2 = EXP2(sa[t][m][2] * SC);
        float p3 = EXP2(sa[t][m][3] * SC);
        lsum[m] += (p0 + p1) + (p2 + p3);
        uint2 pk;
        pk.x = (u32)f2bf(p0) | ((u32)f2bf(p1) << 16);
        pk.y = (u32)f2bf(p2) | ((u32)f2bf(p3) << 16);
        int slot = (2 * t + (g >> 1)) ^ q7;      // s-base = 16t+4g -> slot16
        *(uint2*)((char*)Pw + rowb + slot * 16 + 8 * (g & 1)) = pk;
      }
    }

    // O += P V   (A = P[q][s] read back swizzled; B = V^T[d][s])
    __builtin_amdgcn_s_setprio(1);
#pragma unroll
    for (int kc2 = 0; kc2 < 2; ++kc2) {
      bf16x8 pa[2], vb[8];
#pragma unroll
      for (int m = 0; m < 2; ++m) {
        int q = m * 16 + (lane & 15);
        int slot = (g + 4 * kc2) ^ (q & 7);
        pa[m] = *(const bf16x8*)((char*)Pw + q * 128 + slot * 16);
      }
#pragma unroll
      for (int nd = 0; nd < 8; ++nd) {
        int row = nd * 16 + (lane & 15);
        int ch = kc2 * 4 + g;
        vb[nd] = *(const bf16x8*)(Vc + row * 64 + ((ch ^ (row & 7)) << 3));
      }
#pragma unroll
      for (int m = 0; m < 2; ++m)
#pragma unroll
        for (int nd = 0; nd < 8; ++nd)
          os[m][nd] = MFMA16(pa[m], vb[nd], os[m][nd]);
    }
    __builtin_amdgcn_s_setprio(0);
    __builtin_amdgcn_s_barrier();   // all waves done reading buf[cur]
  }
#undef STAGE

  // finish row sums: combine the 4 lane-groups (each holds 16 of 64 s-cols)
#pragma unroll
  for (int m = 0; m < 2; ++m) {
    float s = lsum[m];
    s += __shfl_xor(s, 16);
    s += __shfl_xor(s, 32);
    lsum[m] = s;  // total for q = 16m + (lane&15), valid in all lanes
  }

  // epilogue: normalize and store X[b*1024+q][h*128+d]
#pragma unroll
  for (int m = 0; m < 2; ++m)
#pragma unroll
    for (int j = 0; j < 4; ++j) {
      float tot = __shfl(lsum[m], 4 * g + j, 64);
      float inv = 1.f / tot;
      int qrow = b * 1024 + q0 + m * 16 + g * 4 + j;
#pragma unroll
      for (int nd = 0; nd < 8; ++nd) {
        int col = h * 128 + nd * 16 + (lane & 15);
        X[(size_t)qrow * 1024 + col] = f2bf(os[m][nd][j] * inv);
      }
    }
}

// ------------- stage 3: X @ proj_w^T + bias -> f32 out ----------------------
// grid (64 m-tiles, 16 n-tiles); BN=64 (NF=2); LDS 24 KB -> 4 blocks/CU
__global__ __launch_bounds__(256, 4) void gemm_bias_kernel(
    const u16* __restrict__ X, const u16* __restrict__ pw,
    const float* __restrict__ pb, float* __restrict__ out) {
  __shared__ alignas(16) u16 A0[64 * 64], B0[32 * 64];
  __shared__ alignas(16) u16 A1[64 * 64], B1[32 * 64];
  int mBase = blockIdx.x * 128;
  int nBase = blockIdx.y * 64;
  f32x4 acc[4][2];
#pragma unroll
  for (int i = 0; i < 4; ++i)
#pragma unroll
    for (int j = 0; j < 2; ++j) acc[i][j] = (f32x4){0.f, 0.f, 0.f, 0.f};
  gemm_core_bk32<2>(X + (size_t)mBase * 1024, pw + (size_t)nBase * 1024, 1024,
                    A0, B0, A1, B1, acc);
  const int lane = threadIdx.x & 63, wid = threadIdx.x >> 6;
  const int wr = wid >> 1, wc = wid & 1;
#pragma unroll
  for (int nf = 0; nf < 2; ++nf) {
    int e = nBase + wc * 32 + nf * 16 + (lane & 15);
    float bv = pb[e];
#pragma unroll
    for (int mf = 0; mf < 4; ++mf)
#pragma unroll
      for (int j = 0; j < 4; ++j) {
        int m = mBase + wr * 64 + mf * 16 + ((lane >> 4) << 2) + j;
        out[(size_t)m * 1024 + e] = acc[mf][nf][j] + bv;
      }
  }
}

extern "C" void kernel_launch(void* const* d_in, const int* in_sizes, int n_in,
                              void* d_out, int out_size, void* d_ws, size_t ws_size,
                              hipStream_t stream) {
  const float* k = (const float*)d_in[0];
  const float* q = (const float*)d_in[1];
  const float* wk = (const float*)d_in[3];
  const float* wq = (const float*)d_in[4];
  const float* pw = (const float*)d_in[5];
  const float* pb = (const float*)d_in[6];
  float* out = (float*)d_out;
  char* ws = (char*)d_ws;

  u16* kbf = (u16*)(ws);                       // 16 MB (reused as X later)
  u16* qbf = (u16*)(ws + (16ull << 20));       // 16 MB
  u16* wTk = (u16*)(ws + (32ull << 20));       // 2 MB
  u16* wTq = (u16*)(ws + (34ull << 20));       // 2 MB
  u16* pwb = (u16*)(ws + (36ull << 20));       // 2 MB
  u16* kx  = (u16*)(ws + (38ull << 20));       // 16 MB
  u16* qx  = (u16*)(ws + (54ull << 20));       // 16 MB
  u16* kxT = (u16*)(ws + (70ull << 20));       // 16 MB
  u16* X   = kbf;                              // alias: k_bf16 dead by then

  cvt_kernel<<<2048, 256, 0, stream>>>(k, kbf, 1048576);
  cvt_kernel<<<2048, 256, 0, stream>>>(q, qbf, 1048576);
  cvt_kernel<<<512, 256, 0, stream>>>(pw, pwb, 131072);
  wtrans_kernel<<<dim3(16, 2, 8), 256, 0, stream>>>(wk, wTk);
  wtrans_kernel<<<dim3(16, 2, 8), 256, 0, stream>>>(wq, wTq);
  gemm_tanh_kernel<<<dim3(64, 8, 2), 256, 0, stream>>>(kbf, qbf, wTk, wTq, kx, qx);
  transpose_kernel<<<dim3(16, 2, 64), 256, 0, stream>>>(kx, kxT);
  attn_kernel<<<dim3(64, 8), 256, 0, stream>>>(qx, kx, kxT, X);
  gemm_bias_kernel<<<dim3(64, 16), 256, 0, stream>>>(X, pwb, pb, out);
}

// Round 7
// 137.366 us; speedup vs baseline: 1.0991x; 1.0991x over previous
//
#include <hip/hip_runtime.h>

typedef unsigned short u16;
typedef unsigned int u32;
typedef __bf16 bf16x8 __attribute__((ext_vector_type(8)));
typedef float f32x4 __attribute__((ext_vector_type(4)));

#define MFMA16(a, b, c) __builtin_amdgcn_mfma_f32_16x16x32_bf16(a, b, c, 0, 0, 0)
#define EXP2(x) __builtin_amdgcn_exp2f(x)

typedef const void __attribute__((address_space(1)))* gas1_t;
typedef void __attribute__((address_space(3)))* las3_t;

__device__ __forceinline__ void gload16(const void* g, void* l) {
  __builtin_amdgcn_global_load_lds((gas1_t)g, (las3_t)l, 16, 0, 0);
}

__device__ __forceinline__ u16 f2bf(float f) {
  union { float f; u32 u; } v; v.f = f;
  u32 r = v.u + 0x7FFFu + ((v.u >> 16) & 1u);
  return (u16)(r >> 16);
}

// fast tanh via native exp2: tanh(x) = (e^2x - 1)/(e^2x + 1); bf16-accurate
__device__ __forceinline__ float fast_tanh(float x) {
  float xc = fminf(fmaxf(x, -20.f), 20.f);
  float t = EXP2(xc * 2.885390081777927f);  // 2*log2(e)
  return (t - 1.0f) * __builtin_amdgcn_rcpf(t + 1.0f);
}

// ---------------- elementwise f32 -> bf16 convert (8 elems/thread) ----------
__global__ __launch_bounds__(256) void cvt_kernel(const float* __restrict__ in,
                                                  u16* __restrict__ out, int n8) {
  int i = blockIdx.x * blockDim.x + threadIdx.x;
  int stride = gridDim.x * blockDim.x;
  for (; i < n8; i += stride) {
    const float4* p = (const float4*)(in + (size_t)i * 8);
    float4 a = p[0], b = p[1];
    u16 t[8];
    t[0] = f2bf(a.x); t[1] = f2bf(a.y); t[2] = f2bf(a.z); t[3] = f2bf(a.w);
    t[4] = f2bf(b.x); t[5] = f2bf(b.y); t[6] = f2bf(b.z); t[7] = f2bf(b.w);
    *(uint4*)(out + (size_t)i * 8) = *(uint4*)t;
  }
}

// ------------- w [H][E=1024][D=128] f32 -> wT [H][D][E] bf16 ----------------
// wT viewed as [1024 n][1024 e] with n = h*128+d: the full B^T matrix.
__global__ __launch_bounds__(256) void wtrans_kernel(const float* __restrict__ w,
                                                     u16* __restrict__ wT) {
  __shared__ float t[64][65];
  int h = blockIdx.z;
  int e0 = blockIdx.x * 64, d0 = blockIdx.y * 64;
  const float* src = w + (size_t)h * 1024 * 128;
  u16* dst = wT + (size_t)h * 128 * 1024;
  int tid = threadIdx.x;
  {
    int row = tid >> 2, c0 = (tid & 3) * 16;
#pragma unroll
    for (int i = 0; i < 4; ++i) {
      float4 v = *(const float4*)(src + (size_t)(e0 + row) * 128 + d0 + c0 + i * 4);
      t[row][c0 + i * 4 + 0] = v.x;
      t[row][c0 + i * 4 + 1] = v.y;
      t[row][c0 + i * 4 + 2] = v.z;
      t[row][c0 + i * 4 + 3] = v.w;
    }
  }
  __syncthreads();
  {
    int dl = tid >> 2, c0 = (tid & 3) * 16;
    u16 tmp[16];
#pragma unroll
    for (int i = 0; i < 16; ++i) tmp[i] = f2bf(t[c0 + i][dl]);
    u16* o = dst + (size_t)(d0 + dl) * 1024 + e0 + c0;
    *(uint4*)o = *(uint4*)tmp;
    *(uint4*)(o + 8) = *(uint4*)(tmp + 8);
  }
}

// ---- big-tile bf16 GEMM core: BM=AR x BN=BR, BK=64, 512 thr (8 waves) ------
// A: [M][K] row-major bf16; B: [N][K] row-major (B^T layout). 2-phase dbuf
// with counted vmcnt (round-5 proven schedule, bigger geometry).
// LDS per buffer: AR*64 + BR*64 bf16; chunk-swizzled (slot = chunk ^ (row&7)).
template <int AR, int BR, int WM, int WN>
__device__ __forceinline__ void gemm_core_big(const u16* __restrict__ Abase,
                                              const u16* __restrict__ Bbase,
                                              int K, u16* lds,
                                              f32x4 (&acc)[AR / (WM * 16)][BR / (WN * 16)]) {
  constexpr int MF = AR / (WM * 16), NFR = BR / (WN * 16);
  constexpr int NA = AR / 64, NB = BR / 64;      // per-thread gloads per tile
  constexpr int AL = AR * 64, BL = BR * 64;      // u16 per buffer
  const int tid = threadIdx.x, lane = tid & 63, wid = tid >> 6;
  const int wr = wid / WN, wc = wid % WN;
  const int l15 = lane & 15, g = lane >> 4;
  u16* A0 = lds;
  u16* B0 = lds + AL;
  u16* A1 = lds + AL + BL;
  u16* B1 = lds + 2 * AL + BL;
  const int nkt = K >> 6;  // even, >= 2

#define STGX(dst, srcb, NI, kt_)                                                \
  _Pragma("unroll") for (int i_ = 0; i_ < (NI); ++i_) {                         \
    int c = (wid * (NI) + i_) * 64 + lane;                                      \
    int row = c >> 3, slot = c & 7, src = slot ^ (row & 7);                     \
    gload16((const char*)(srcb) + ((size_t)row * K + (kt_) * 64 + src * 8) * 2, \
            (char*)(dst) + (wid * (NI) + i_) * 1024);                           \
  }

#define VWAIT()                                                                 \
  do {                                                                          \
    if constexpr (NA + NB == 8) asm volatile("s_waitcnt vmcnt(8)" ::: "memory");\
    else                        asm volatile("s_waitcnt vmcnt(6)" ::: "memory");\
  } while (0)

#define CMPX(Al, Bl)                                                            \
  do {                                                                          \
    __builtin_amdgcn_s_setprio(1);                                              \
    _Pragma("unroll") for (int kc = 0; kc < 2; ++kc) {                          \
      bf16x8 af[MF], bb[NFR];                                                   \
      _Pragma("unroll") for (int f = 0; f < MF; ++f) {                          \
        int rp = wr * (AR / WM) + f * 16 + l15;                                 \
        af[f] = *(const bf16x8*)((Al) + rp * 64 + (((kc * 4 + g) ^ (rp & 7)) << 3)); \
      }                                                                         \
      _Pragma("unroll") for (int f = 0; f < NFR; ++f) {                         \
        int rp = wc * (BR / WN) + f * 16 + l15;                                 \
        bb[f] = *(const bf16x8*)((Bl) + rp * 64 + (((kc * 4 + g) ^ (rp & 7)) << 3)); \
      }                                                                         \
      _Pragma("unroll") for (int mf = 0; mf < MF; ++mf)                         \
        _Pragma("unroll") for (int nf = 0; nf < NFR; ++nf)                      \
          acc[mf][nf] = MFMA16(af[mf], bb[nf], acc[mf][nf]);                    \
    }                                                                           \
    __builtin_amdgcn_s_setprio(0);                                              \
  } while (0)

  STGX(A0, Abase, NA, 0);
  STGX(B0, Bbase, NB, 0);
  for (int it = 0; it < nkt / 2 - 1; ++it) {
    STGX(A1, Abase, NA, 2 * it + 1);
    STGX(B1, Bbase, NB, 2 * it + 1);
    VWAIT();                                // tile 2it drained; 2it+1 in flight
    __builtin_amdgcn_s_barrier();
    CMPX(A0, B0);
    __builtin_amdgcn_s_barrier();           // all waves done reading buf0
    STGX(A0, Abase, NA, 2 * it + 2);
    STGX(B0, Bbase, NB, 2 * it + 2);
    VWAIT();
    __builtin_amdgcn_s_barrier();
    CMPX(A1, B1);
    __builtin_amdgcn_s_barrier();
  }
  STGX(A1, Abase, NA, nkt - 1);
  STGX(B1, Bbase, NB, nkt - 1);
  VWAIT();
  __builtin_amdgcn_s_barrier();
  CMPX(A0, B0);
  asm volatile("s_waitcnt vmcnt(0)" ::: "memory");
  __builtin_amdgcn_s_barrier();
  CMPX(A1, B1);
#undef STGX
#undef VWAIT
#undef CMPX
}

// ------------- stage 1: projection + tanh -> bf16 (single big GEMM) ---------
// C[s][n=h*128+d] = tanh(A[s][:] . W^T[n][:]); grid (32 m, 4 n, 2 tensors),
// 256x256 tile, 8 waves (2Mx4N), LDS 128 KB, 256 blocks = 1/CU.
__global__ __launch_bounds__(512, 2) void gemm_tanh_kernel(
    const u16* __restrict__ Ak, const u16* __restrict__ Aq,
    const u16* __restrict__ wTk, const u16* __restrict__ wTq,
    u16* __restrict__ kxo, u16* __restrict__ qxo) {
  __shared__ alignas(16) u16 lds[2 * (256 * 64 + 256 * 64)];  // 128 KB
  const u16* A; const u16* W; u16* C;
  if (blockIdx.z == 0) { A = Ak; W = wTk; C = kxo; }
  else { A = Aq; W = wTq; C = qxo; }
  int mBase = blockIdx.x * 256;
  int nBase = blockIdx.y * 256;
  f32x4 acc[8][4];
#pragma unroll
  for (int i = 0; i < 8; ++i)
#pragma unroll
    for (int j = 0; j < 4; ++j) acc[i][j] = (f32x4){0.f, 0.f, 0.f, 0.f};
  gemm_core_big<256, 256, 2, 4>(A + (size_t)mBase * 1024,
                                W + (size_t)nBase * 1024, 1024, lds, acc);
  const int lane = threadIdx.x & 63, wid = threadIdx.x >> 6;
  const int wr = wid >> 2, wc = wid & 3, l15 = lane & 15, g = lane >> 4;
#pragma unroll
  for (int mf = 0; mf < 8; ++mf)
#pragma unroll
    for (int nf = 0; nf < 4; ++nf)
#pragma unroll
      for (int j = 0; j < 4; ++j) {
        int m = mBase + wr * 128 + mf * 16 + g * 4 + j;
        int n = nBase + wc * 64 + nf * 16 + l15;
        int h = n >> 7, d = n & 127;
        C[(size_t)h * 8192 * 128 + (size_t)m * 128 + d] =
            f2bf(fast_tanh(acc[mf][nf][j]));
      }
}

// ------------- kx [h][b*1024+s][128] -> kxT [h][b][128][1024] ---------------
// grid (16 s-tiles, 2 d-tiles, 64 hb)
__global__ __launch_bounds__(256) void transpose_kernel(const u16* __restrict__ kx,
                                                        u16* __restrict__ kxT) {
  __shared__ u16 t[64][72];
  int hb = blockIdx.z;
  const u16* src = kx + (size_t)hb * 1024 * 128;
  u16* dst = kxT + (size_t)hb * 128 * 1024;
  int s0 = blockIdx.x * 64, d0 = blockIdx.y * 64;
  int tid = threadIdx.x;
#pragma unroll
  for (int r = 0; r < 2; ++r) {
    int row = r * 32 + (tid >> 3), c8 = (tid & 7) * 8;
    uint4 v = *(const uint4*)(src + (size_t)(s0 + row) * 128 + d0 + c8);
    *(uint4*)&t[row][c8] = v;
  }
  __syncthreads();
#pragma unroll
  for (int r = 0; r < 2; ++r) {
    int dl = r * 32 + (tid >> 3), s8 = (tid & 7) * 8;
    u16 tmp[8];
#pragma unroll
    for (int i = 0; i < 8; ++i) tmp[i] = t[s8 + i][dl];
    *(uint4*)(dst + (size_t)(d0 + dl) * 1024 + s0 + s8) = *(uint4*)tmp;
  }
}

// ---------------------------- flash attention -------------------------------
// grid (64 hb, 8 q-tiles); 4 waves x 32 q-rows; KV tiles of 64
// Swapped QK^T (S^T = mfma(K, Q)) -> P packs in-register, 8 x ds_write_b64.
// No-max softmax (tanh-bounded scores). Dbuf K/V staging with counted vmcnt.
__global__ __launch_bounds__(256, 2) void attn_kernel(const u16* __restrict__ qx,
                                                      const u16* __restrict__ kx,
                                                      const u16* __restrict__ kxT,
                                                      u16* __restrict__ X) {
  __shared__ alignas(16) u16 Klds[2][64 * 128];   // [s][d], 16 chunks/row, swizzled
  __shared__ alignas(16) u16 Vlds[2][128 * 64];   // [d][s], 8 chunks/row, swizzled
  __shared__ alignas(16) u16 Plds[4][32 * 64];    // per-wave [q][s], slot16-swizzled
  const int tid = threadIdx.x, lane = tid & 63, wid = tid >> 6;
  const int g = lane >> 4;                        // 16-lane group 0..3
  const int hb = blockIdx.x, qt = blockIdx.y, h = hb >> 3, b = hb & 7;
  const u16* qxh = qx + ((size_t)h * 8192 + (size_t)b * 1024) * 128;
  const u16* kxh = kx + ((size_t)h * 8192 + (size_t)b * 1024) * 128;
  const u16* kxTh = kxT + (size_t)hb * 128 * 1024;
  const int q0 = qt * 128 + wid * 32;
  const float SC = 0.08838834764831845f * 1.44269504088896340f; // 1/sqrt(128)*log2e

#define STAGE(buf, kt_)                                                        \
  do {                                                                         \
    _Pragma("unroll") for (int i_ = 0; i_ < 4; ++i_) {                         \
      int cIdx = (wid * 4 + i_) * 64 + lane;                                   \
      {                                                                        \
        int row = cIdx >> 4, slot = cIdx & 15;                                 \
        int src = slot ^ (row & 7);                                            \
        gload16((const char*)kxh + (size_t)((kt_) * 64 + row) * 256 + src * 16,\
                (char*)&Klds[buf][0] + (wid * 4 + i_) * 1024);                 \
      }                                                                        \
      {                                                                        \
        int row = cIdx >> 3, slot = cIdx & 7;                                  \
        int src = slot ^ (row & 7);                                            \
        gload16((const char*)kxTh + (size_t)row * 2048 + (kt_) * 128 + src * 16,\
                (char*)&Vlds[buf][0] + (wid * 4 + i_) * 1024);                 \
      }                                                                        \
    }                                                                          \
  } while (0)

  bf16x8 qa[2][4];
#pragma unroll
  for (int m = 0; m < 2; ++m)
#pragma unroll
    for (int kc = 0; kc < 4; ++kc)
      qa[m][kc] = *(const bf16x8*)(qxh + (size_t)(q0 + m * 16 + (lane & 15)) * 128
                                   + kc * 32 + g * 8);

  f32x4 os[2][8];
#pragma unroll
  for (int i = 0; i < 2; ++i)
#pragma unroll
    for (int j = 0; j < 8; ++j) os[i][j] = (f32x4){0.f, 0.f, 0.f, 0.f};
  float lsum[2] = {0.f, 0.f};   // partial row-sums for q = 16m + (lane&15)

  u16* Pw = &Plds[wid][0];

  STAGE(0, 0);  // prologue: tile 0 in flight

  for (int kt = 0; kt < 16; ++kt) {
    const int cur = kt & 1;
    if (kt < 15) {
      STAGE(cur ^ 1, kt + 1);                       // issue next tile (8 loads)
      asm volatile("s_waitcnt vmcnt(8)" ::: "memory");  // tile kt drained
    } else {
      asm volatile("s_waitcnt vmcnt(0)" ::: "memory");
    }
    __builtin_amdgcn_s_barrier();                   // tile kt visible to all

    const u16* Kc = &Klds[cur][0];
    const u16* Vc = &Vlds[cur][0];

    // S^T = K Q^T: sa[t][m][j] = S[q = 16m+(lane&15)][s = 16t + 4g + j]
    f32x4 sa[4][2];
#pragma unroll
    for (int i = 0; i < 4; ++i)
#pragma unroll
      for (int j = 0; j < 2; ++j) sa[i][j] = (f32x4){0.f, 0.f, 0.f, 0.f};
    __builtin_amdgcn_s_setprio(1);
#pragma unroll
    for (int kc = 0; kc < 4; ++kc) {
      bf16x8 kb[4];
#pragma unroll
      for (int t = 0; t < 4; ++t) {
        int row = t * 16 + (lane & 15);
        int ch = kc * 4 + g;
        kb[t] = *(const bf16x8*)(Kc + row * 128 + ((ch ^ (row & 7)) << 3));
      }
#pragma unroll
      for (int t = 0; t < 4; ++t)
#pragma unroll
        for (int m = 0; m < 2; ++m)
          sa[t][m] = MFMA16(kb[t], qa[m][kc], sa[t][m]);
    }
    __builtin_amdgcn_s_setprio(0);

    // no-max softmax: p = exp2(s*SC); pack 4 bf16 -> one ds_write_b64.
#pragma unroll
    for (int m = 0; m < 2; ++m) {
      int q = m * 16 + (lane & 15);
      int rowb = q * 128, q7 = q & 7;
#pragma unroll
      for (int t = 0; t < 4; ++t) {
        float p0 = EXP2(sa[t][m][0] * SC);
        float p1 = EXP2(sa[t][m][1] * SC);
        float p2 = EXP2(sa[t][m][2] * SC);
        float p3 = EXP2(sa[t][m][3] * SC);
        lsum[m] += (p0 + p1) + (p2 + p3);
        uint2 pk;
        pk.x = (u32)f2bf(p0) | ((u32)f2bf(p1) << 16);
        pk.y = (u32)f2bf(p2) | ((u32)f2bf(p3) << 16);
        int slot = (2 * t + (g >> 1)) ^ q7;      // s-base = 16t+4g -> slot16
        *(uint2*)((char*)Pw + rowb + slot * 16 + 8 * (g & 1)) = pk;
      }
    }

    // O += P V   (A = P[q][s] read back swizzled; B = V^T[d][s])
    __builtin_amdgcn_s_setprio(1);
#pragma unroll
    for (int kc2 = 0; kc2 < 2; ++kc2) {
      bf16x8 pa[2], vb[8];
#pragma unroll
      for (int m = 0; m < 2; ++m) {
        int q = m * 16 + (lane & 15);
        int slot = (g + 4 * kc2) ^ (q & 7);
        pa[m] = *(const bf16x8*)((char*)Pw + q * 128 + slot * 16);
      }
#pragma unroll
      for (int nd = 0; nd < 8; ++nd) {
        int row = nd * 16 + (lane & 15);
        int ch = kc2 * 4 + g;
        vb[nd] = *(const bf16x8*)(Vc + row * 64 + ((ch ^ (row & 7)) << 3));
      }
#pragma unroll
      for (int m = 0; m < 2; ++m)
#pragma unroll
        for (int nd = 0; nd < 8; ++nd)
          os[m][nd] = MFMA16(pa[m], vb[nd], os[m][nd]);
    }
    __builtin_amdgcn_s_setprio(0);
    __builtin_amdgcn_s_barrier();   // all waves done reading buf[cur]
  }
#undef STAGE

  // finish row sums: combine the 4 lane-groups (each holds 16 of 64 s-cols)
#pragma unroll
  for (int m = 0; m < 2; ++m) {
    float s = lsum[m];
    s += __shfl_xor(s, 16);
    s += __shfl_xor(s, 32);
    lsum[m] = s;  // total for q = 16m + (lane&15), valid in all lanes
  }

  // epilogue: normalize and store X[b*1024+q][h*128+d]
#pragma unroll
  for (int m = 0; m < 2; ++m)
#pragma unroll
    for (int j = 0; j < 4; ++j) {
      float tot = __shfl(lsum[m], 4 * g + j, 64);
      float inv = 1.f / tot;
      int qrow = b * 1024 + q0 + m * 16 + g * 4 + j;
#pragma unroll
      for (int nd = 0; nd < 8; ++nd) {
        int col = h * 128 + nd * 16 + (lane & 15);
        X[(size_t)qrow * 1024 + col] = f2bf(os[m][nd][j] * inv);
      }
    }
}

// ------------- stage 3: X @ proj_w^T + bias -> f32 out ----------------------
// grid (32 m, 8 n); 256x128 tile, 8 waves (4Mx2N), LDS 96 KB, 256 blocks.
__global__ __launch_bounds__(512, 2) void gemm_bias_kernel(
    const u16* __restrict__ X, const u16* __restrict__ pw,
    const float* __restrict__ pb, float* __restrict__ out) {
  __shared__ alignas(16) u16 lds[2 * (256 * 64 + 128 * 64)];  // 96 KB
  int mBase = blockIdx.x * 256;
  int nBase = blockIdx.y * 128;
  f32x4 acc[4][4];
#pragma unroll
  for (int i = 0; i < 4; ++i)
#pragma unroll
    for (int j = 0; j < 4; ++j) acc[i][j] = (f32x4){0.f, 0.f, 0.f, 0.f};
  gemm_core_big<256, 128, 4, 2>(X + (size_t)mBase * 1024,
                                pw + (size_t)nBase * 1024, 1024, lds, acc);
  const int lane = threadIdx.x & 63, wid = threadIdx.x >> 6;
  const int wr = wid >> 1, wc = wid & 1, l15 = lane & 15, g = lane >> 4;
#pragma unroll
  for (int nf = 0; nf < 4; ++nf) {
    int e = nBase + wc * 64 + nf * 16 + l15;
    float bv = pb[e];
#pragma unroll
    for (int mf = 0; mf < 4; ++mf)
#pragma unroll
      for (int j = 0; j < 4; ++j) {
        int m = mBase + wr * 64 + mf * 16 + g * 4 + j;
        out[(size_t)m * 1024 + e] = acc[mf][nf][j] + bv;
      }
  }
}

extern "C" void kernel_launch(void* const* d_in, const int* in_sizes, int n_in,
                              void* d_out, int out_size, void* d_ws, size_t ws_size,
                              hipStream_t stream) {
  const float* k = (const float*)d_in[0];
  const float* q = (const float*)d_in[1];
  const float* wk = (const float*)d_in[3];
  const float* wq = (const float*)d_in[4];
  const float* pw = (const float*)d_in[5];
  const float* pb = (const float*)d_in[6];
  float* out = (float*)d_out;
  char* ws = (char*)d_ws;

  u16* kbf = (u16*)(ws);                       // 16 MB (reused as X later)
  u16* qbf = (u16*)(ws + (16ull << 20));       // 16 MB
  u16* wTk = (u16*)(ws + (32ull << 20));       // 2 MB
  u16* wTq = (u16*)(ws + (34ull << 20));       // 2 MB
  u16* pwb = (u16*)(ws + (36ull << 20));       // 2 MB
  u16* kx  = (u16*)(ws + (38ull << 20));       // 16 MB
  u16* qx  = (u16*)(ws + (54ull << 20));       // 16 MB
  u16* kxT = (u16*)(ws + (70ull << 20));       // 16 MB
  u16* X   = kbf;                              // alias: k_bf16 dead by then

  cvt_kernel<<<2048, 256, 0, stream>>>(k, kbf, 1048576);
  cvt_kernel<<<2048, 256, 0, stream>>>(q, qbf, 1048576);
  cvt_kernel<<<512, 256, 0, stream>>>(pw, pwb, 131072);
  wtrans_kernel<<<dim3(16, 2, 8), 256, 0, stream>>>(wk, wTk);
  wtrans_kernel<<<dim3(16, 2, 8), 256, 0, stream>>>(wq, wTq);
  gemm_tanh_kernel<<<dim3(32, 4, 2), 512, 0, stream>>>(kbf, qbf, wTk, wTq, kx, qx);
  transpose_kernel<<<dim3(16, 2, 64), 256, 0, stream>>>(kx, kxT);
  attn_kernel<<<dim3(64, 8), 256, 0, stream>>>(qx, kx, kxT, X);
  gemm_bias_kernel<<<dim3(32, 8), 512, 0, stream>>>(X, pwb, pb, out);
}